// Round 2
// 524.829 us; speedup vs baseline: 1.3124x; 1.3124x over previous
//
#include <hip/hip_runtime.h>
#include <hip/hip_bf16.h>
#include <stdint.h>

#define NB   16
#define CIN  512
#define COUT 512
#define STY  512
#define HH   64
#define WW   64
#define KT   9          // 3x3 taps
#define KDIM (CIN*KT)   // 4608
#define HP   66         // padded spatial
#define PIX  (HH*WW)    // 4096
#define EPSV 1e-8f

#define SLOT 16384      // elems per ring slot: A 8192 + B 8192 (32 KB)
#define NKT  144        // K-tiles of 32: 9 taps * 16

typedef __attribute__((ext_vector_type(8))) __bf16 bf16x8;
typedef __attribute__((ext_vector_type(4))) float floatx4;
typedef unsigned short ushort;

__device__ __forceinline__ ushort f32_to_bf16(float f) {
    union { float f; uint32_t u; } v; v.f = f;
    uint32_t u = v.u;
    u += 0x7fffu + ((u >> 16) & 1u);   // RNE
    return (ushort)(u >> 16);
}

__device__ __forceinline__ void async16(const void* g, void* l) {
    __builtin_amdgcn_global_load_lds(
        (const __attribute__((address_space(1))) uint32_t*)g,
        (__attribute__((address_space(3))) uint32_t*)l, 16, 0, 0);
}

// ---------------- kernel 1: style linear: s[n][ci] ----------------
__global__ void __launch_bounds__(256) style_kernel(
    const float* __restrict__ style, const float* __restrict__ style_w,
    const float* __restrict__ style_b, float* __restrict__ s) {
    const int n = blockIdx.x;
    const int ci = blockIdx.y * 64 + (threadIdx.x >> 2);
    const int q = threadIdx.x & 3;
    const float4* wv = (const float4*)(style_w + (size_t)ci * STY);
    const float4* sv = (const float4*)(style + (size_t)n * STY);
    float acc = 0.f;
    #pragma unroll 8
    for (int j = q; j < STY / 4; j += 4) {
        float4 a = wv[j], b = sv[j];
        acc += a.x * b.x + a.y * b.y + a.z * b.z + a.w * b.w;
    }
    acc += __shfl_down(acc, 2, 4);
    acc += __shfl_down(acc, 1, 4);
    if (q == 0) s[(size_t)n * CIN + ci] = acc + style_b[ci];
}

// ------- kernel 2: modulate + demod + transpose to Wt[n][co][kk][ci] bf16 -------
__global__ void __launch_bounds__(256) modw_kernel(
    const float* __restrict__ weight, const float* __restrict__ s,
    ushort* __restrict__ Wt) {
    __shared__ float wL[KDIM];   // 18432 B
    __shared__ float sL[CIN];    // 2048 B
    __shared__ float red[4];
    const int co = blockIdx.x, n = blockIdx.y, t = threadIdx.x;
    const float2* wv = (const float2*)(weight + (size_t)co * KDIM);
    float2* wLv = (float2*)wL;
    #pragma unroll
    for (int i = 0; i < 9; ++i) wLv[t + 256 * i] = wv[t + 256 * i];
    ((float2*)sL)[t] = ((const float2*)(s + (size_t)n * CIN))[t];
    __syncthreads();
    float m[18];
    float sum = 0.f;
    #pragma unroll
    for (int c = 0; c < 2; ++c) {
        int ci = 2 * t + c;
        float sm = sL[ci];
        #pragma unroll
        for (int kk = 0; kk < 9; ++kk) {
            float v = wL[ci * 9 + kk] * sm;
            m[c * 9 + kk] = v;
            sum += v * v;
        }
    }
    for (int off = 32; off > 0; off >>= 1) sum += __shfl_down(sum, off, 64);
    if ((t & 63) == 0) red[t >> 6] = sum;
    __syncthreads();
    const float demod = rsqrtf(red[0] + red[1] + red[2] + red[3] + EPSV);
    uint32_t* orow = (uint32_t*)(Wt + (size_t)(n * COUT + co) * KDIM);
    #pragma unroll
    for (int kk = 0; kk < 9; ++kk) {
        uint32_t lo = (uint32_t)f32_to_bf16(m[kk] * demod);
        uint32_t hi = (uint32_t)f32_to_bf16(m[9 + kk] * demod);
        orow[kk * 256 + t] = lo | (hi << 16);
    }
}

// ------- kernel 3a: zero the padding borders of xt[n][66][66][512] (bf16) -------
__global__ void __launch_bounds__(256) zborder_kernel(unsigned long long* __restrict__ xt8) {
    int idx = blockIdx.x * 256 + threadIdx.x;  // 16*260*128 exactly
    int k = idx & 127;
    int rem = idx >> 7;
    int slot = rem % 260;
    int n = rem / 260;
    int hp, wp;
    if (slot < 66)       { hp = 0;  wp = slot; }
    else if (slot < 132) { hp = 65; wp = slot - 66; }
    else { int r = slot - 132; hp = 1 + (r >> 1); wp = (r & 1) ? 65 : 0; }
    xt8[(size_t)((n * HP + hp) * HP + wp) * 128 + k] = 0ull;
}

// ------- kernel 3b: NCHW fp32 -> padded NHWC bf16 transpose -------
__global__ void __launch_bounds__(256) xpose_kernel(
    const float* __restrict__ x, ushort* __restrict__ xt) {
    const int h = blockIdx.x;   // 0..63
    const int n = blockIdx.y;
    const int t = threadIdx.x;
    __shared__ float tile[64][68];
    for (int ci0 = 0; ci0 < CIN; ci0 += 64) {
        #pragma unroll
        for (int r = 0; r < 4; ++r) {
            int cil = r * 16 + (t >> 4);
            int w4 = (t & 15) * 4;
            float4 v = *(const float4*)&x[(((size_t)n * CIN + ci0 + cil) * HH + h) * WW + w4];
            *(float4*)&tile[cil][w4] = v;
        }
        __syncthreads();
        #pragma unroll
        for (int r = 0; r < 8; ++r) {
            int w = (t >> 5) + r * 8;
            int cil = 2 * (t & 31);
            uint32_t lo = (uint32_t)f32_to_bf16(tile[cil][w]);
            uint32_t hi = (uint32_t)f32_to_bf16(tile[cil + 1][w]);
            *(uint32_t*)&xt[(((size_t)n * HP + h + 1) * HP + (w + 1)) * CIN + ci0 + cil] =
                lo | (hi << 16);
        }
        __syncthreads();
    }
}

// ------- kernel 4: implicit-GEMM conv, 256x256 tile, 8 waves, ring-4 LDS -------
// Deep pipeline: counted vmcnt(8) (3 K-tiles in flight), raw s_barrier, XOR-swizzled
// LDS (pre-swizzled global source, linear global_load_lds dest), setprio on MFMA.
template<int VMC, bool STAGE>
__device__ __forceinline__ void ktile(
    int kt, short* lds_, const ushort* __restrict__ Wt, const ushort* __restrict__ xt,
    size_t gA0, size_t gA1, size_t gB0, size_t gB1,
    int dA0, int dA1, int dB0, int dB1,
    int aBase, int bBase, floatx4 (&acc)[8][4]) {
    short* sbase = lds_ + (kt & 3) * SLOT;
    // --- K-tile boundary: counted drain (oldest 4 = this tile's loads), barrier ---
    __builtin_amdgcn_sched_barrier(0);
    if constexpr (VMC == 8)      asm volatile("s_waitcnt vmcnt(8)" ::: "memory");
    else if constexpr (VMC == 4) asm volatile("s_waitcnt vmcnt(4)" ::: "memory");
    else                         asm volatile("s_waitcnt vmcnt(0)" ::: "memory");
    __builtin_amdgcn_s_barrier();
    __builtin_amdgcn_sched_barrier(0);

    // --- phase A: read a[0..3] + all b, issue A-chunk of kt+3, MFMA M-half 0 ---
    bf16x8 af[4], bv[4];
    #pragma unroll
    for (int i = 0; i < 4; ++i) af[i] = *(const bf16x8*)(sbase + aBase + i * 512);
    #pragma unroll
    for (int i = 0; i < 4; ++i) bv[i] = *(const bf16x8*)(sbase + bBase + i * 512);
    if constexpr (STAGE) {
        short* dbase = lds_ + ((kt + 3) & 3) * SLOT;
        size_t off = (size_t)(kt + 3) * 32;     // A is K-linear: tap*512+cs = kt*32
        async16(Wt + gA0 + off, dbase + dA0);
        async16(Wt + gA1 + off, dbase + dA1);
    }
    __builtin_amdgcn_sched_barrier(0);
    __builtin_amdgcn_s_barrier();
    __builtin_amdgcn_sched_barrier(0);
    __builtin_amdgcn_s_setprio(1);
    #pragma unroll
    for (int mi = 0; mi < 4; ++mi)
        #pragma unroll
        for (int ni = 0; ni < 4; ++ni)
            acc[mi][ni] = __builtin_amdgcn_mfma_f32_16x16x32_bf16(
                af[mi], bv[ni], acc[mi][ni], 0, 0, 0);
    __builtin_amdgcn_s_setprio(0);
    __builtin_amdgcn_sched_barrier(0);
    __builtin_amdgcn_s_barrier();
    __builtin_amdgcn_sched_barrier(0);

    // --- phase B: read a[4..7], issue B-chunk of kt+3, MFMA M-half 1 ---
    #pragma unroll
    for (int i = 0; i < 4; ++i) af[i] = *(const bf16x8*)(sbase + aBase + 2048 + i * 512);
    if constexpr (STAGE) {
        short* dbase = lds_ + ((kt + 3) & 3) * SLOT;
        int ktp = kt + 3;
        int tap = ktp >> 4;
        int kh = tap / 3, kw = tap - kh * 3;
        size_t off = (size_t)(kh * HP + kw) * CIN + (size_t)((ktp & 15) << 5);
        async16(xt + gB0 + off, dbase + dB0);
        async16(xt + gB1 + off, dbase + dB1);
    }
    __builtin_amdgcn_sched_barrier(0);
    __builtin_amdgcn_s_barrier();
    __builtin_amdgcn_sched_barrier(0);
    __builtin_amdgcn_s_setprio(1);
    #pragma unroll
    for (int mi = 0; mi < 4; ++mi)
        #pragma unroll
        for (int ni = 0; ni < 4; ++ni)
            acc[4 + mi][ni] = __builtin_amdgcn_mfma_f32_16x16x32_bf16(
                af[mi], bv[ni], acc[4 + mi][ni], 0, 0, 0);
    __builtin_amdgcn_s_setprio(0);
    __builtin_amdgcn_sched_barrier(0);
}

__global__ void __launch_bounds__(512, 2) conv_kernel(
    const ushort* __restrict__ Wt, const ushort* __restrict__ xt,
    const float* __restrict__ noise, const float* __restrict__ nw_p,
    float* __restrict__ out) {
    __shared__ short lds[4 * SLOT];        // 128 KiB: 4 ring slots of (A 16K + B 16K)
    const int t = threadIdx.x;             // 0..511
    const int bid = blockIdx.x;            // 0..511
    // XCD-bijective swizzle: XCD owns 4 (n,co-half) pairs; pixel tile fastest.
    const int xcd = bid & 7;
    const int slot = bid >> 3;             // 0..63
    const int p = slot & 15;               // pixel tile
    const int pg = xcd * 4 + (slot >> 4);  // 0..31 = (n, co-half)
    const int n = pg >> 1;
    const int co0 = (pg & 1) * 256;
    const int pos0 = p * 256;
    const int h0 = p * 4;                  // 4 image rows per pixel tile

    const int l = t & 63;
    const int wv = t >> 6;                 // 8 waves: 2M x 4N
    const int wr = wv >> 2;                // M half (128 rows)
    const int wc = wv & 3;                 // N quarter (64 pixels)
    const int lrow = l & 15;
    const int lkg = l >> 4;
    // XOR bank swizzle: granule ^= (row>>1)&3 ; on reads row≡lrow (mod 16)
    const int kcol = (lkg ^ ((l >> 1) & 3)) * 8;
    const int aBase = (wr * 128 + lrow) * 32 + kcol;          // + mi*512
    const int bBase = 8192 + (wc * 64 + lrow) * 32 + kcol;    // + ni*512

    // staging bases: thread covers elems [q*4096 + t*8, +8) of the 256x32 chunk,
    // LDS dest linear, global source pre-swizzled (rule #21)
    size_t gAq[2], gBq[2];
    int dAq[2], dBq[2];
    #pragma unroll
    for (int q = 0; q < 2; ++q) {
        int e = q * 4096 + t * 8;
        int row = e >> 5;                      // 0..255
        int gr = (e >> 3) & 3;
        int grs = gr ^ ((row >> 1) & 3);
        gAq[q] = (size_t)(n * COUT + co0 + row) * KDIM + grs * 8;
        int prow = row >> 6, pcol = row & 63;  // row = pixel index in tile
        gBq[q] = ((size_t)(n * HP + h0 + prow) * HP + pcol) * CIN + grs * 8;
        dAq[q] = q * 4096 + t * 8;
        dBq[q] = 8192 + q * 4096 + t * 8;
    }

    floatx4 acc[8][4];
    #pragma unroll
    for (int i = 0; i < 8; ++i)
        #pragma unroll
        for (int j = 0; j < 4; ++j) acc[i][j] = (floatx4){0.f, 0.f, 0.f, 0.f};

    // prologue: stage K-tiles 0..2 (all in tap 0 -> B offset = kt*32 too)
    #pragma unroll
    for (int ktp = 0; ktp < 3; ++ktp) {
        short* dbase = lds + ktp * SLOT;
        size_t off = (size_t)ktp * 32;
        async16(Wt + gAq[0] + off, dbase + dAq[0]);
        async16(Wt + gAq[1] + off, dbase + dAq[1]);
        async16(xt + gBq[0] + off, dbase + dBq[0]);
        async16(xt + gBq[1] + off, dbase + dBq[1]);
    }

    // main loop: 144 K-tiles (BK=32), prefetch kt+3 into ring slot (kt+3)&3.
    // unroll 1: keep ONE copy of the 32-MFMA body (ring-index kt&3 invites
    // unroll-by-4 -> code bloat / compile blowup; slot calc is 2 VALU ops).
    #pragma unroll 1
    for (int kt = 0; kt < 141; ++kt)
        ktile<8, true>(kt, lds, Wt, xt, gAq[0], gAq[1], gBq[0], gBq[1],
                       dAq[0], dAq[1], dBq[0], dBq[1], aBase, bBase, acc);
    ktile<8, false>(141, lds, Wt, xt, gAq[0], gAq[1], gBq[0], gBq[1],
                    dAq[0], dAq[1], dBq[0], dBq[1], aBase, bBase, acc);
    ktile<4, false>(142, lds, Wt, xt, gAq[0], gAq[1], gBq[0], gBq[1],
                    dAq[0], dAq[1], dBq[0], dBq[1], aBase, bBase, acc);
    ktile<0, false>(143, lds, Wt, xt, gAq[0], gAq[1], gBq[0], gBq[1],
                    dAq[0], dAq[1], dBq[0], dBq[1], aBase, bBase, acc);

    // epilogue: + noise_weight*noise, LeakyReLU(0.2). C/D: col=lane&15, row=quad*4+r
    const float nwv = nw_p[0];
    float nz[4];
    #pragma unroll
    for (int ni = 0; ni < 4; ++ni)
        nz[ni] = nwv * noise[(size_t)n * PIX + pos0 + wc * 64 + ni * 16 + lrow];
    #pragma unroll
    for (int mi = 0; mi < 8; ++mi) {
        #pragma unroll
        for (int r = 0; r < 4; ++r) {
            int cout = co0 + wr * 128 + mi * 16 + lkg * 4 + r;
            float* orow = out + ((size_t)n * COUT + cout) * PIX + pos0 + wc * 64;
            #pragma unroll
            for (int ni = 0; ni < 4; ++ni) {
                float v = acc[mi][ni][r] + nz[ni];
                v = v >= 0.f ? v : 0.2f * v;
                orow[ni * 16 + lrow] = v;
            }
        }
    }
}

extern "C" void kernel_launch(void* const* d_in, const int* in_sizes, int n_in,
                              void* d_out, int out_size, void* d_ws, size_t ws_size,
                              hipStream_t stream) {
    const float* x       = (const float*)d_in[0];
    const float* style   = (const float*)d_in[1];
    const float* noise   = (const float*)d_in[2];
    const float* weight  = (const float*)d_in[3];
    const float* style_w = (const float*)d_in[4];
    const float* style_b = (const float*)d_in[5];
    const float* noise_w = (const float*)d_in[6];
    float* out = (float*)d_out;

    char* ws = (char*)d_ws;
    ushort* Wt = (ushort*)ws;                                   // 16*512*9*512*2 = 75,497,472 B
    ushort* xt = (ushort*)(ws + 75497472);                      // 16*66*66*512*2 = 71,368,704 B
    float*  s  = (float*)(ws + 75497472 + 71368704);            // 32 KB

    hipLaunchKernelGGL(style_kernel,   dim3(16, 8),    dim3(256), 0, stream,
                       style, style_w, style_b, s);
    hipLaunchKernelGGL(modw_kernel,    dim3(512, 16),  dim3(256), 0, stream,
                       weight, s, Wt);
    hipLaunchKernelGGL(zborder_kernel, dim3(2080),     dim3(256), 0, stream,
                       (unsigned long long*)xt);
    hipLaunchKernelGGL(xpose_kernel,   dim3(64, 16),   dim3(256), 0, stream,
                       x, xt);
    hipLaunchKernelGGL(conv_kernel,    dim3(512),      dim3(512), 0, stream,
                       Wt, xt, noise, noise_w, out);
}